// Round 4
// baseline (144.109 us; speedup 1.0000x reference)
//
#include <hip/hip_runtime.h>
#include <math.h>

// Problem constants (from reference)
#define BB 16
#define NN 65536
#define DD 8
#define OUT_SIZE 4096
#define IN_SIZE 4096

#define BLOCKS_PER_B 32
#define NC (NN / BLOCKS_PER_B)   // 2048 tuples per block
#define BLOCK_THREADS 1024       // 16 waves/block

// y[b,o] = bias[o]  (output is re-poisoned before every timed launch)
__global__ void init_out(const float* __restrict__ bias, float* __restrict__ y) {
    int i = blockIdx.x * blockDim.x + threadIdx.x;     // 0 .. B*OUT_SIZE-1
    y[i] = bias[i & (OUT_SIZE - 1)];
}

__global__ __launch_bounds__(BLOCK_THREADS, 8)
void hyper_scatter(const float* __restrict__ x,
                   const float* __restrict__ means,
                   const float* __restrict__ sigmas,
                   const float* __restrict__ values,
                   const float* __restrict__ noise,
                   float* __restrict__ y) {
    __shared__ float ys[OUT_SIZE];   // per-(b,chunk) partial output, 16 KB
    // NOTE: x is NOT staged in LDS anymore — the random x-gather goes to
    // L1/L2 (x[b] is 16 KB, cache-resident) on the TA pipe, so it overlaps
    // with ds_add atomics on the DS pipe instead of serializing behind them.

    const int b     = blockIdx.x / BLOCKS_PER_B;
    const int chunk = blockIdx.x % BLOCKS_PER_B;
    const int tid   = threadIdx.x;
    const float* xb = x + (size_t)b * IN_SIZE;

    // zero partial accumulator (coalesced float4)
    {
        float4* ydst = (float4*)ys;
        if (tid < OUT_SIZE / 4) {           // 1024 threads cover all 1024 float4s
            ydst[tid] = make_float4(0.f, 0.f, 0.f, 0.f);
        }
    }
    __syncthreads();

    const int n0 = chunk * NC;
    #pragma unroll
    for (int nl = tid; nl < NC; nl += BLOCK_THREADS) {   // exactly 2 iterations
        const size_t base = (size_t)b * NN + (size_t)(n0 + nl);
        const float2 mean  = ((const float2*)means)[base];
        const float  sigma = sigmas[base];
        const float  value = values[base];

        // noise[b,n,:,:] = 16 contiguous floats, 64B-aligned
        const float4* np4 = (const float4*)(noise + base * (size_t)(DD * 2));
        float4 nz0 = np4[0], nz1 = np4[1], nz2 = np4[2], nz3 = np4[3];
        float nr[DD * 2] = { nz0.x, nz0.y, nz0.z, nz0.w,
                             nz1.x, nz1.y, nz1.z, nz1.w,
                             nz2.x, nz2.y, nz2.z, nz2.w,
                             nz3.x, nz3.y, nz3.z, nz3.w };

        const float neg_inv_2s2 = -0.5f / (sigma * sigma);

        float p[DD];
        int   oi[DD], ii[DD];
        float psum = 0.f;
        #pragma unroll
        for (int d = 0; d < DD; ++d) {
            // EXACT sample rounding: mul-then-add, no FMA contraction,
            // so rintf() flips the same half-integer cases as np.round.
            float s0 = __fadd_rn(__fmul_rn(nr[2 * d],     sigma), mean.x);
            float s1 = __fadd_rn(__fmul_rn(nr[2 * d + 1], sigma), mean.y);
            float d0 = s0 - mean.x;             // reference's diff (post-roundtrip)
            float d1 = s1 - mean.y;
            float q  = d0 * d0 + d1 * d1;
            float pd = __expf(q * neg_inv_2s2); // 1/(2πσ²) cancels in normalization
            p[d] = pd;
            psum += pd;
            oi[d] = (int)fminf(fmaxf(rintf(s0), 0.f), (float)(OUT_SIZE - 1));
            ii[d] = (int)fminf(fmaxf(rintf(s1), 0.f), (float)(IN_SIZE - 1));
        }

        // x-gather on the TA/L1 pipe (issue all 8 loads before the atomics
        // so they pipeline; compiler will keep them in flight via vmcnt)
        float xv[DD];
        #pragma unroll
        for (int d = 0; d < DD; ++d) xv[d] = xb[ii[d]];

        const float wscale = value / psum;      // one divide per tuple
        #pragma unroll
        for (int d = 0; d < DD; ++d) {
            // LDS fp atomic: ds_add_f32, random addr
            atomicAdd(&ys[oi[d]], wscale * p[d] * xv[d]);
        }
    }
    __syncthreads();

    // one HW fp atomic per output element per block (no CAS loop)
    float* yb = y + (size_t)b * OUT_SIZE;
    #pragma unroll
    for (int o = tid; o < OUT_SIZE; o += BLOCK_THREADS) {
        unsafeAtomicAdd(&yb[o], ys[o]);
    }
}

extern "C" void kernel_launch(void* const* d_in, const int* in_sizes, int n_in,
                              void* d_out, int out_size, void* d_ws, size_t ws_size,
                              hipStream_t stream) {
    const float* x      = (const float*)d_in[0];   // [B, IN_SIZE]
    const float* means  = (const float*)d_in[1];   // [B, N, 2]
    const float* sigmas = (const float*)d_in[2];   // [B, N]
    const float* values = (const float*)d_in[3];   // [B, N]
    const float* bias   = (const float*)d_in[4];   // [OUT_SIZE]
    const float* noise  = (const float*)d_in[5];   // [B, N, D, 2]
    float* y = (float*)d_out;                      // [B, OUT_SIZE]

    init_out<<<(BB * OUT_SIZE) / 256, 256, 0, stream>>>(bias, y);
    hyper_scatter<<<BB * BLOCKS_PER_B, BLOCK_THREADS, 0, stream>>>(
        x, means, sigmas, values, noise, y);
}

// Round 5
// 141.294 us; speedup vs baseline: 1.0199x; 1.0199x over previous
//
#include <hip/hip_runtime.h>
#include <math.h>

// Problem constants (from reference)
#define BB 16
#define NN 65536
#define DD 8
#define OUT_SIZE 4096
#define IN_SIZE 4096

#define BLOCKS_PER_B 32
#define NC (NN / BLOCKS_PER_B)   // 2048 tuples per block
#define BLOCK_THREADS 1024       // 16 waves/block

// y[b,o] = bias[o]  (output is re-poisoned before every timed launch)
__global__ void init_out(const float* __restrict__ bias, float* __restrict__ y) {
    int i = blockIdx.x * blockDim.x + threadIdx.x;     // 0 .. B*OUT_SIZE-1
    y[i] = bias[i & (OUT_SIZE - 1)];
}

__global__ __launch_bounds__(BLOCK_THREADS, 8)
void hyper_scatter(const float* __restrict__ x,
                   const float* __restrict__ means,
                   const float* __restrict__ sigmas,
                   const float* __restrict__ values,
                   const float* __restrict__ noise,
                   float* __restrict__ y) {
    __shared__ float ys[OUT_SIZE];   // per-(b,chunk) partial output, 16 KB

    const int b     = blockIdx.x / BLOCKS_PER_B;
    const int chunk = blockIdx.x % BLOCKS_PER_B;
    const int tid   = threadIdx.x;
    const float* xb = x + (size_t)b * IN_SIZE;

    // zero partial accumulator (coalesced float4)
    {
        float4* ydst = (float4*)ys;
        if (tid < OUT_SIZE / 4) {           // 1024 threads cover all 1024 float4s
            ydst[tid] = make_float4(0.f, 0.f, 0.f, 0.f);
        }
    }
    __syncthreads();

    const int n0 = chunk * NC;
    #pragma unroll
    for (int nl = tid; nl < NC; nl += BLOCK_THREADS) {   // exactly 2 iterations
        const size_t base = (size_t)b * NN + (size_t)(n0 + nl);
        const float2 mean  = ((const float2*)means)[base];
        const float  sigma = sigmas[base];
        const float  value = values[base];

        // noise[b,n,:,:] = 16 contiguous floats, 64B-aligned
        const float4* np4 = (const float4*)(noise + base * (size_t)(DD * 2));
        float4 nz0 = np4[0], nz1 = np4[1], nz2 = np4[2], nz3 = np4[3];
        float nr[DD * 2] = { nz0.x, nz0.y, nz0.z, nz0.w,
                             nz1.x, nz1.y, nz1.z, nz1.w,
                             nz2.x, nz2.y, nz2.z, nz2.w,
                             nz3.x, nz3.y, nz3.z, nz3.w };

        const float neg_inv_2s2 = -0.5f / (sigma * sigma);

        float p[DD];
        int   oi[DD], ii[DD];
        float psum = 0.f;
        #pragma unroll
        for (int d = 0; d < DD; ++d) {
            // EXACT sample rounding: mul-then-add, no FMA contraction,
            // so rintf() flips the same half-integer cases as np.round.
            float s0 = __fadd_rn(__fmul_rn(nr[2 * d],     sigma), mean.x);
            float s1 = __fadd_rn(__fmul_rn(nr[2 * d + 1], sigma), mean.y);
            float d0 = s0 - mean.x;             // reference's diff (post-roundtrip)
            float d1 = s1 - mean.y;
            float q  = d0 * d0 + d1 * d1;
            float pd = __expf(q * neg_inv_2s2); // 1/(2πσ²) cancels in normalization
            p[d] = pd;
            psum += pd;
            oi[d] = (int)fminf(fmaxf(rintf(s0), 0.f), (float)(OUT_SIZE - 1));
            ii[d] = (int)fminf(fmaxf(rintf(s1), 0.f), (float)(IN_SIZE - 1));
        }
        const float wscale = value / psum;      // one divide per tuple

        // ---- within-tuple dedupe: samples cluster within ~±2σ of the mean,
        // so the 8 rounded (oi,ii) pairs often collide (avg ~6.2 unique).
        // Merge duplicate keys on the (idle) VALU pipe, then exec-predicate
        // the gather+atomic: masked-off lanes issue NO memory/LDS requests.
        int   key[DD];
        float w[DD];
        #pragma unroll
        for (int d = 0; d < DD; ++d) {
            key[d] = (oi[d] << 12) | ii[d];
            w[d]   = p[d];
        }
        // Accumulate each later duplicate into ALL matching earlier slots.
        // Safe: only earlier slots are augmented, and a slot is read as a
        // source (w[d]) strictly before it can ever be augmented; extra
        // adds land only in dead (dup) slots which are never scattered.
        #pragma unroll
        for (int d = 1; d < DD; ++d) {
            #pragma unroll
            for (int j = 0; j < d; ++j) {
                if (key[j] == key[d]) w[j] += w[d];   // cndmask-add, no branch
            }
        }
        bool dup[DD];
        #pragma unroll
        for (int d = 0; d < DD; ++d) {
            bool dd = false;
            #pragma unroll
            for (int j = 0; j < d; ++j) dd = dd || (key[j] == key[d]);
            dup[d] = dd;
        }

        // pass 1: predicated gathers (issue together so they pipeline)
        float xv[DD];
        #pragma unroll
        for (int d = 0; d < DD; ++d) {
            xv[d] = 0.f;
            if (!dup[d]) xv[d] = xb[ii[d]];
        }
        // pass 2: predicated LDS atomics
        #pragma unroll
        for (int d = 0; d < DD; ++d) {
            if (!dup[d]) atomicAdd(&ys[oi[d]], wscale * w[d] * xv[d]);
        }
    }
    __syncthreads();

    // one HW fp atomic per output element per block (no CAS loop)
    float* yb = y + (size_t)b * OUT_SIZE;
    #pragma unroll
    for (int o = tid; o < OUT_SIZE; o += BLOCK_THREADS) {
        unsafeAtomicAdd(&yb[o], ys[o]);
    }
}

extern "C" void kernel_launch(void* const* d_in, const int* in_sizes, int n_in,
                              void* d_out, int out_size, void* d_ws, size_t ws_size,
                              hipStream_t stream) {
    const float* x      = (const float*)d_in[0];   // [B, IN_SIZE]
    const float* means  = (const float*)d_in[1];   // [B, N, 2]
    const float* sigmas = (const float*)d_in[2];   // [B, N]
    const float* values = (const float*)d_in[3];   // [B, N]
    const float* bias   = (const float*)d_in[4];   // [OUT_SIZE]
    const float* noise  = (const float*)d_in[5];   // [B, N, D, 2]
    float* y = (float*)d_out;                      // [B, OUT_SIZE]

    init_out<<<(BB * OUT_SIZE) / 256, 256, 0, stream>>>(bias, y);
    hyper_scatter<<<BB * BLOCKS_PER_B, BLOCK_THREADS, 0, stream>>>(
        x, means, sigmas, values, noise, y);
}